// Round 1
// baseline (291.666 us; speedup 1.0000x reference)
//
#include <hip/hip_runtime.h>

#define NTOK 16384
#define DIM  2048
#define NE   64
#define TPB  64      // tokens per block
#define DC   32      // d-chunk staged in LDS
#define XPITCH 33    // pad: 2-way bank alias only (free)
#define LPITCH 65

__global__ __launch_bounds__(256) void moe_router_kernel(
    const float* __restrict__ X, const float* __restrict__ W,
    const float* __restrict__ B, float* __restrict__ out)
{
    __shared__ float lds[TPB * LPITCH];   // 16.6 KB, reused for x-stage then logits
    const int tid  = threadIdx.x;
    const int lane = tid & 63;            // token within block
    const int wv   = tid >> 6;            // expert group 0..3
    const int e0   = wv * 16;
    const int t0   = blockIdx.x * TPB;

    float acc[16];
#pragma unroll
    for (int i = 0; i < 16; ++i) acc[i] = 0.f;

    // ---- prefetch first x chunk into registers ----
    const int q0 = tid, q1 = tid + 256;          // float4 ids 0..511
    const int r0 = q0 >> 3, c0 = (q0 & 7) << 2;  // 8 float4 per 32-wide row
    const int r1 = q1 >> 3, c1 = (q1 & 7) << 2;
    float4 pf0 = *(const float4*)&X[(t0 + r0) * DIM + c0];
    float4 pf1 = *(const float4*)&X[(t0 + r1) * DIM + c1];

    for (int dc = 0; dc < DIM; dc += DC) {
        // store prefetched chunk to LDS
        lds[r0 * XPITCH + c0 + 0] = pf0.x;
        lds[r0 * XPITCH + c0 + 1] = pf0.y;
        lds[r0 * XPITCH + c0 + 2] = pf0.z;
        lds[r0 * XPITCH + c0 + 3] = pf0.w;
        lds[r1 * XPITCH + c1 + 0] = pf1.x;
        lds[r1 * XPITCH + c1 + 1] = pf1.y;
        lds[r1 * XPITCH + c1 + 2] = pf1.z;
        lds[r1 * XPITCH + c1 + 3] = pf1.w;
        __syncthreads();

        // prefetch next chunk (overlaps with compute below)
        if (dc + DC < DIM) {
            pf0 = *(const float4*)&X[(t0 + r0) * DIM + dc + DC + c0];
            pf1 = *(const float4*)&X[(t0 + r1) * DIM + dc + DC + c1];
        }

        // compute: 1 LDS read + 16 FMA per j, w rows are wave-uniform -> s_loads
#pragma unroll 8
        for (int j = 0; j < DC; ++j) {
            float xv = lds[lane * XPITCH + j];
            const float4* wr4 = (const float4*)&W[(dc + j) * NE + e0];
            float4 w0 = wr4[0], w1 = wr4[1], w2 = wr4[2], w3 = wr4[3];
            acc[0]  = fmaf(xv, w0.x, acc[0]);   acc[1]  = fmaf(xv, w0.y, acc[1]);
            acc[2]  = fmaf(xv, w0.z, acc[2]);   acc[3]  = fmaf(xv, w0.w, acc[3]);
            acc[4]  = fmaf(xv, w1.x, acc[4]);   acc[5]  = fmaf(xv, w1.y, acc[5]);
            acc[6]  = fmaf(xv, w1.z, acc[6]);   acc[7]  = fmaf(xv, w1.w, acc[7]);
            acc[8]  = fmaf(xv, w2.x, acc[8]);   acc[9]  = fmaf(xv, w2.y, acc[9]);
            acc[10] = fmaf(xv, w2.z, acc[10]);  acc[11] = fmaf(xv, w2.w, acc[11]);
            acc[12] = fmaf(xv, w3.x, acc[12]);  acc[13] = fmaf(xv, w3.y, acc[13]);
            acc[14] = fmaf(xv, w3.z, acc[14]);  acc[15] = fmaf(xv, w3.w, acc[15]);
        }
        __syncthreads();
    }

    // ---- write logits (+bias) to LDS, pitch 65 ----
#pragma unroll
    for (int i = 0; i < 16; ++i)
        lds[lane * LPITCH + e0 + i] = acc[i] + B[e0 + i];
    __syncthreads();

    float* out_logits = out;
    float* out_nv     = out + (size_t)NTOK * NE;
    float* out_idx    = out_nv + (size_t)NTOK * 2;

    // coalesced logits store: 4096 floats per block as float4
#pragma unroll
    for (int k = 0; k < 4; ++k) {
        int q = tid + k * 256;        // float4 id 0..1023
        int r = q >> 4;               // 16 float4 per 64-wide row
        int c = (q & 15) << 2;
        float4 v;
        v.x = lds[r * LPITCH + c + 0];
        v.y = lds[r * LPITCH + c + 1];
        v.z = lds[r * LPITCH + c + 2];
        v.w = lds[r * LPITCH + c + 3];
        *(float4*)&out_logits[(size_t)(t0 + r) * NE + c] = v;
    }

    // top-2 + renormalize: one thread per token (threads 0..63)
    if (tid < TPB) {
        float m1 = -1e30f, m2 = -1e30f;
        int   i1 = 0, i2 = 0;
        for (int e = 0; e < NE; ++e) {
            float v = lds[tid * LPITCH + e];
            if (v > m1)      { m2 = m1; i2 = i1; m1 = v; i1 = e; }
            else if (v > m2) { m2 = v;  i2 = e; }
        }
        // renorm: softmax Z cancels; max == m1; clip(1e-6) can never bind (p1 >= 1/64)
        float e2  = expf(m2 - m1);
        float inv = 1.f / (1.f + e2);
        int t = t0 + tid;
        out_nv[t * 2 + 0]  = inv;
        out_nv[t * 2 + 1]  = e2 * inv;
        out_idx[t * 2 + 0] = (float)i1;
        out_idx[t * 2 + 1] = (float)i2;
    }
}

extern "C" void kernel_launch(void* const* d_in, const int* in_sizes, int n_in,
                              void* d_out, int out_size, void* d_ws, size_t ws_size,
                              hipStream_t stream) {
    const float* X = (const float*)d_in[0];
    const float* W = (const float*)d_in[1];
    const float* B = (const float*)d_in[2];
    float* out = (float*)d_out;
    dim3 grid(NTOK / TPB);   // 256 blocks
    dim3 block(256);
    hipLaunchKernelGGL(moe_router_kernel, grid, block, 0, stream, X, W, B, out);
}

// Round 2
// 77.156 us; speedup vs baseline: 3.7802x; 3.7802x over previous
//
#include <hip/hip_runtime.h>

#define NTOK 16384
#define DIM  2048
#define NE   64
#define TPB  64          // tokens per block
#define KG   4           // K-split across waves
#define EGN  4           // expert-group count
#define KPW  (DIM / KG)  // 512 k per wave
#define EPW  (NE / EGN)  // 16 experts per wave
#define LP   65          // padded LDS pitch (bank = (row+col)%32, 2-way = free)

__global__ __launch_bounds__(1024) void router_main(
    const float* __restrict__ X, const float* __restrict__ W,
    const float* __restrict__ B, float* __restrict__ out)
{
    __shared__ float red[KG][TPB][LP];   // 66.6 KB k-partial buffer
    __shared__ float lg[TPB][LP];        // 16.6 KB final logits for top-2

    const int tid  = threadIdx.x;
    const int lane = tid & 63;
    const int wv   = tid >> 6;                                   // 0..15
    const int eg   = __builtin_amdgcn_readfirstlane(wv & 3);     // expert group
    const int kg   = __builtin_amdgcn_readfirstlane(wv >> 2);    // k group
    const int t0   = blockIdx.x * TPB;

    // lane's token row, this wave's K-range
    const float* xrow  = X + (size_t)(t0 + lane) * DIM + kg * KPW;
    // wave-uniform W base (scalar path): rows kg*KPW.., experts eg*16..
    const float* wbase = W + (size_t)kg * KPW * NE + eg * EPW;

    float acc[EPW];
#pragma unroll
    for (int i = 0; i < EPW; ++i) acc[i] = 0.f;

    for (int kc = 0; kc < KPW; kc += 8) {
        float4 xa = *(const float4*)(xrow + kc);
        float4 xb = *(const float4*)(xrow + kc + 4);
        float xs[8] = {xa.x, xa.y, xa.z, xa.w, xb.x, xb.y, xb.z, xb.w};
#pragma unroll
        for (int j = 0; j < 8; ++j) {
            // uniform address -> s_load_dwordx4 x4 ; fmac operands: v,s,v
            const float4* wr = (const float4*)(wbase + (size_t)(kc + j) * NE);
            float4 w0 = wr[0], w1 = wr[1], w2 = wr[2], w3 = wr[3];
            float xv = xs[j];
            acc[0]  = fmaf(xv, w0.x, acc[0]);   acc[1]  = fmaf(xv, w0.y, acc[1]);
            acc[2]  = fmaf(xv, w0.z, acc[2]);   acc[3]  = fmaf(xv, w0.w, acc[3]);
            acc[4]  = fmaf(xv, w1.x, acc[4]);   acc[5]  = fmaf(xv, w1.y, acc[5]);
            acc[6]  = fmaf(xv, w1.z, acc[6]);   acc[7]  = fmaf(xv, w1.w, acc[7]);
            acc[8]  = fmaf(xv, w2.x, acc[8]);   acc[9]  = fmaf(xv, w2.y, acc[9]);
            acc[10] = fmaf(xv, w2.z, acc[10]);  acc[11] = fmaf(xv, w2.w, acc[11]);
            acc[12] = fmaf(xv, w3.x, acc[12]);  acc[13] = fmaf(xv, w3.y, acc[13]);
            acc[14] = fmaf(xv, w3.z, acc[14]);  acc[15] = fmaf(xv, w3.w, acc[15]);
        }
    }

    // ---- k-partials to LDS; bank = (lane + e)%32 -> 2-way, free ----
#pragma unroll
    for (int i = 0; i < EPW; ++i)
        red[kg][lane][eg * EPW + i] = acc[i];
    __syncthreads();

    float* out_nv  = out + (size_t)NTOK * NE;
    float* out_idx = out_nv + (size_t)NTOK * 2;

    // ---- reduce over KG, add bias, store logits (coalesced float4) ----
    {
        const int rt = tid >> 4;          // token 0..63
        const int re = (tid & 15) * 4;    // expert col 0,4,..,60
        float4 s;
        s.x = red[0][rt][re + 0] + red[1][rt][re + 0] + red[2][rt][re + 0] + red[3][rt][re + 0];
        s.y = red[0][rt][re + 1] + red[1][rt][re + 1] + red[2][rt][re + 1] + red[3][rt][re + 1];
        s.z = red[0][rt][re + 2] + red[1][rt][re + 2] + red[2][rt][re + 2] + red[3][rt][re + 2];
        s.w = red[0][rt][re + 3] + red[1][rt][re + 3] + red[2][rt][re + 3] + red[3][rt][re + 3];
        float4 bb = *(const float4*)(B + re);
        s.x += bb.x; s.y += bb.y; s.z += bb.z; s.w += bb.w;
        *(float4*)&out[(size_t)(t0 + rt) * NE + re] = s;
        lg[rt][re + 0] = s.x;
        lg[rt][re + 1] = s.y;
        lg[rt][re + 2] = s.z;
        lg[rt][re + 3] = s.w;
    }
    __syncthreads();

    // ---- top-2 + renormalize (softmax Z cancels; clip can't bind) ----
    if (tid < TPB) {
        float m1 = -1e30f, m2 = -1e30f;
        int   i1 = 0, i2 = 0;
        for (int e = 0; e < NE; ++e) {
            float v = lg[tid][e];
            if (v > m1)      { m2 = m1; i2 = i1; m1 = v; i1 = e; }
            else if (v > m2) { m2 = v;  i2 = e; }
        }
        float e2  = expf(m2 - m1);
        float inv = 1.f / (1.f + e2);
        int t = t0 + tid;
        out_nv[t * 2 + 0]  = inv;
        out_nv[t * 2 + 1]  = e2 * inv;
        out_idx[t * 2 + 0] = (float)i1;
        out_idx[t * 2 + 1] = (float)i2;
    }
}

extern "C" void kernel_launch(void* const* d_in, const int* in_sizes, int n_in,
                              void* d_out, int out_size, void* d_ws, size_t ws_size,
                              hipStream_t stream) {
    const float* X = (const float*)d_in[0];
    const float* W = (const float*)d_in[1];
    const float* B = (const float*)d_in[2];
    float* out = (float*)d_out;
    dim3 grid(NTOK / TPB);   // 256 blocks, 1/CU
    dim3 block(1024);        // 16 waves: 4 expert-groups x 4 k-groups
    hipLaunchKernelGGL(router_main, grid, block, 0, stream, X, W, B, out);
}

// Round 3
// 75.953 us; speedup vs baseline: 3.8401x; 1.0158x over previous
//
#include <hip/hip_runtime.h>

#define NTOK 16384
#define DIM  2048
#define NE   64
#define TPB  64          // tokens per block
#define KG   4           // K-split across waves (16 k each within a 64-k chunk)
#define EGN  4           // expert groups (16 experts each)
#define EPW  16
#define DC   64          // k-chunk staged in LDS
#define NCHUNK (DIM / DC)
#define LP   65

__global__ __launch_bounds__(1024) void router_main(
    const float* __restrict__ X, const float* __restrict__ W,
    const float* __restrict__ B, float* __restrict__ out)
{
    // pitch 17 float4 = 68 dwords: b128 read bank-start (4*tok+16j)%32 -> even 8-way spread
    __shared__ float4 xbuf[2][TPB][17];        // 34.8 KB, double-buffered X chunk
    __shared__ float  red[KG][TPB][LP];        // 66.6 KB k-partials
    __shared__ float  lg[TPB][LP];             // 16.6 KB logits for top-2

    const int tid  = threadIdx.x;
    const int lane = tid & 63;
    const int wv   = tid >> 6;                                   // 0..15
    const int eg   = __builtin_amdgcn_readfirstlane(wv & 3);     // expert group
    const int kg   = __builtin_amdgcn_readfirstlane(wv >> 2);    // k group
    const int t0   = blockIdx.x * TPB;

    // staging geometry: thread q loads X[t0 + (q>>4)][kc + 4*(q&15) .. +3]
    const int sr = tid >> 4;          // token row 0..63
    const int sc = tid & 15;          // float4 col 0..15

    float acc[EPW];
#pragma unroll
    for (int i = 0; i < EPW; ++i) acc[i] = 0.f;

    // prefetch chunk 0
    float4 pf = *(const float4*)&X[(size_t)(t0 + sr) * DIM + 4 * sc];

    for (int c = 0; c < NCHUNK; ++c) {
        const int b = c & 1;
        xbuf[b][sr][sc] = pf;
        __syncthreads();

        if (c + 1 < NCHUNK)
            pf = *(const float4*)&X[(size_t)(t0 + sr) * DIM + (c + 1) * DC + 4 * sc];

        // wave-uniform W pointer for this chunk: rows c*64 + kg*16 + j, cols eg*16..
        const float* wp = W + (size_t)(c * DC + kg * EPW) * NE + eg * EPW;

#pragma unroll
        for (int jj = 0; jj < 4; ++jj) {
            float4 x4 = xbuf[b][lane][kg * 4 + jj];   // ds_read_b128
            float xs[4] = {x4.x, x4.y, x4.z, x4.w};
#pragma unroll
            for (int m = 0; m < 4; ++m) {
                const int j = 4 * jj + m;
                const float4* wr = (const float4*)(wp + (size_t)j * NE);
                float4 w0 = wr[0], w1 = wr[1], w2 = wr[2], w3 = wr[3];  // s_load
                float xv = xs[m];
                acc[0]  = fmaf(xv, w0.x, acc[0]);   acc[1]  = fmaf(xv, w0.y, acc[1]);
                acc[2]  = fmaf(xv, w0.z, acc[2]);   acc[3]  = fmaf(xv, w0.w, acc[3]);
                acc[4]  = fmaf(xv, w1.x, acc[4]);   acc[5]  = fmaf(xv, w1.y, acc[5]);
                acc[6]  = fmaf(xv, w1.z, acc[6]);   acc[7]  = fmaf(xv, w1.w, acc[7]);
                acc[8]  = fmaf(xv, w2.x, acc[8]);   acc[9]  = fmaf(xv, w2.y, acc[9]);
                acc[10] = fmaf(xv, w2.z, acc[10]);  acc[11] = fmaf(xv, w2.w, acc[11]);
                acc[12] = fmaf(xv, w3.x, acc[12]);  acc[13] = fmaf(xv, w3.y, acc[13]);
                acc[14] = fmaf(xv, w3.z, acc[14]);  acc[15] = fmaf(xv, w3.w, acc[15]);
            }
        }
        __syncthreads();   // all waves done with xbuf[b] before it's overwritten (c+2)
    }

    // ---- k-partials to LDS; bank = (lane + e)%32 -> 2-way, free ----
#pragma unroll
    for (int i = 0; i < EPW; ++i)
        red[kg][lane][eg * EPW + i] = acc[i];
    __syncthreads();

    float* out_nv  = out + (size_t)NTOK * NE;
    float* out_idx = out_nv + (size_t)NTOK * 2;

    // ---- reduce over KG, add bias, store logits (coalesced float4) ----
    {
        const int rt = tid >> 4;
        const int re = (tid & 15) * 4;
        float4 s;
        s.x = red[0][rt][re + 0] + red[1][rt][re + 0] + red[2][rt][re + 0] + red[3][rt][re + 0];
        s.y = red[0][rt][re + 1] + red[1][rt][re + 1] + red[2][rt][re + 1] + red[3][rt][re + 1];
        s.z = red[0][rt][re + 2] + red[1][rt][re + 2] + red[2][rt][re + 2] + red[3][rt][re + 2];
        s.w = red[0][rt][re + 3] + red[1][rt][re + 3] + red[2][rt][re + 3] + red[3][rt][re + 3];
        float4 bb = *(const float4*)(B + re);
        s.x += bb.x; s.y += bb.y; s.z += bb.z; s.w += bb.w;
        *(float4*)&out[(size_t)(t0 + rt) * NE + re] = s;
        lg[rt][re + 0] = s.x;
        lg[rt][re + 1] = s.y;
        lg[rt][re + 2] = s.z;
        lg[rt][re + 3] = s.w;
    }
    __syncthreads();

    // ---- top-2 + renormalize (softmax Z cancels; clip can't bind) ----
    if (tid < TPB) {
        float m1 = -1e30f, m2 = -1e30f;
        int   i1 = 0, i2 = 0;
        for (int e = 0; e < NE; ++e) {
            float v = lg[tid][e];
            if (v > m1)      { m2 = m1; i2 = i1; m1 = v; i1 = e; }
            else if (v > m2) { m2 = v;  i2 = e; }
        }
        float e2  = expf(m2 - m1);
        float inv = 1.f / (1.f + e2);
        int t = t0 + tid;
        out_nv[t * 2 + 0]  = inv;
        out_nv[t * 2 + 1]  = e2 * inv;
        out_idx[t * 2 + 0] = (float)i1;
        out_idx[t * 2 + 1] = (float)i2;
    }
}

extern "C" void kernel_launch(void* const* d_in, const int* in_sizes, int n_in,
                              void* d_out, int out_size, void* d_ws, size_t ws_size,
                              hipStream_t stream) {
    const float* X = (const float*)d_in[0];
    const float* W = (const float*)d_in[1];
    const float* B = (const float*)d_in[2];
    float* out = (float*)d_out;
    dim3 grid(NTOK / TPB);   // 256 blocks, 1/CU
    dim3 block(1024);        // 16 waves: 4 expert-groups x 4 k-groups
    hipLaunchKernelGGL(router_main, grid, block, 0, stream, X, W, B, out);
}

// Round 4
// 57.080 us; speedup vs baseline: 5.1098x; 1.3307x over previous
//
#include <hip/hip_runtime.h>

#define NTOK 16384
#define DIM  2048
#define NE   64
#define TPB  64
#define KG   4                 // K-split across waves
#define KPW  (DIM / KG)        // 512 k per wave
#define KSTEPS (KPW / 32)      // 16 mfma k-steps per wave
#define NKS_ALL (DIM / 32)     // 64 total k-steps
#define LP   65

typedef __attribute__((ext_vector_type(8))) short  short8;   // 8 bf16 (4 VGPRs)
typedef __attribute__((ext_vector_type(4))) float  f32x4;

static __device__ __forceinline__ unsigned short f2bf(float f) {
    unsigned u = __float_as_uint(f);
    unsigned r = (u + 0x7fffu + ((u >> 16) & 1u)) >> 16;   // RNE
    return (unsigned short)r;
}
static __device__ __forceinline__ float bf2f(unsigned short h) {
    return __uint_as_float(((unsigned)h) << 16);
}

// ---- prologue: split W into hi/lo bf16 and pack in MFMA B-fragment order ----
// B-frag (16x16x32): lane l holds col=l&15, k = (l>>4)*8 + j (j=0..7)
// WF[etile][kstep][lane][j], etile=e/16, kstep=k/32
__global__ void pack_w(const float* __restrict__ W,
                       unsigned short* __restrict__ WH,
                       unsigned short* __restrict__ WL) {
    int idx = blockIdx.x * 256 + threadIdx.x;       // 0 .. DIM*NE-1
    if (idx >= DIM * NE) return;
    int k = idx / NE, e = idx % NE;
    float w = W[idx];
    unsigned short h = f2bf(w);
    unsigned short l = f2bf(w - bf2f(h));
    int etile = e >> 4, col = e & 15;
    int kstep = k >> 5, lsub = (k >> 3) & 3, j = k & 7;
    size_t off = (((size_t)etile * NKS_ALL + kstep) * 64 + (lsub * 16 + col)) * 8 + j;
    WH[off] = h;
    WL[off] = l;
}

// ---- main: 3-pass split-bf16 MFMA router ----
__global__ __launch_bounds__(1024) void router_mfma(
    const float* __restrict__ X,
    const unsigned short* __restrict__ WH,
    const unsigned short* __restrict__ WL,
    const float* __restrict__ B, float* __restrict__ out)
{
    __shared__ float red[KG][TPB][LP];   // 66.6 KB k-partials
    __shared__ float lg[TPB][LP];        // 16.6 KB logits for top-2

    const int tid  = threadIdx.x;
    const int lane = tid & 63;
    const int wv   = tid >> 6;                                 // 0..15
    const int wt   = __builtin_amdgcn_readfirstlane(wv & 3);   // token 16-tile
    const int kg   = __builtin_amdgcn_readfirstlane(wv >> 2);  // k group
    const int t0   = blockIdx.x * TPB;

    const int arow = lane & 15;           // A row (token within tile)
    const int koff = (lane >> 4) * 8;     // k offset within 32-step

    const float* xp = X + (size_t)(t0 + wt * 16 + arow) * DIM + kg * KPW + koff;

    f32x4 acc[4];
#pragma unroll
    for (int et = 0; et < 4; ++et) acc[et] = (f32x4){0.f, 0.f, 0.f, 0.f};

#pragma unroll 2
    for (int s = 0; s < KSTEPS; ++s) {
        // A fragment: 8 consecutive fp32, split to hi/lo bf16
        float4 xa = *(const float4*)(xp + s * 32);
        float4 xb = *(const float4*)(xp + s * 32 + 4);
        float xs[8] = {xa.x, xa.y, xa.z, xa.w, xb.x, xb.y, xb.z, xb.w};
        short8 ah, al;
#pragma unroll
        for (int j = 0; j < 8; ++j) {
            unsigned short h = f2bf(xs[j]);
            ah[j] = (short)h;
            al[j] = (short)f2bf(xs[j] - bf2f(h));
        }
        const int ks = kg * KSTEPS + s;   // absolute k-step
#pragma unroll
        for (int et = 0; et < 4; ++et) {
            size_t foff = (((size_t)et * NKS_ALL + ks) * 64 + lane) * 8;
            short8 bh = *(const short8*)(WH + foff);   // coalesced dwordx4
            short8 bl = *(const short8*)(WL + foff);
            acc[et] = __builtin_amdgcn_mfma_f32_16x16x32_bf16(ah, bh, acc[et], 0, 0, 0);
            acc[et] = __builtin_amdgcn_mfma_f32_16x16x32_bf16(ah, bl, acc[et], 0, 0, 0);
            acc[et] = __builtin_amdgcn_mfma_f32_16x16x32_bf16(al, bh, acc[et], 0, 0, 0);
        }
    }

    // C frag: col = lane&15, row = (lane>>4)*4 + r  (m89-verified)
#pragma unroll
    for (int et = 0; et < 4; ++et)
#pragma unroll
        for (int r = 0; r < 4; ++r)
            red[kg][wt * 16 + (lane >> 4) * 4 + r][et * 16 + (lane & 15)] = acc[et][r];
    __syncthreads();

    float* out_nv  = out + (size_t)NTOK * NE;
    float* out_idx = out_nv + (size_t)NTOK * 2;

    // ---- reduce over KG, add bias, store logits (coalesced float4) ----
    {
        const int rt = tid >> 4;
        const int re = (tid & 15) * 4;
        float4 s;
        s.x = red[0][rt][re + 0] + red[1][rt][re + 0] + red[2][rt][re + 0] + red[3][rt][re + 0];
        s.y = red[0][rt][re + 1] + red[1][rt][re + 1] + red[2][rt][re + 1] + red[3][rt][re + 1];
        s.z = red[0][rt][re + 2] + red[1][rt][re + 2] + red[2][rt][re + 2] + red[3][rt][re + 2];
        s.w = red[0][rt][re + 3] + red[1][rt][re + 3] + red[2][rt][re + 3] + red[3][rt][re + 3];
        float4 bb = *(const float4*)(B + re);
        s.x += bb.x; s.y += bb.y; s.z += bb.z; s.w += bb.w;
        *(float4*)&out[(size_t)(t0 + rt) * NE + re] = s;
        lg[rt][re + 0] = s.x;
        lg[rt][re + 1] = s.y;
        lg[rt][re + 2] = s.z;
        lg[rt][re + 3] = s.w;
    }
    __syncthreads();

    // ---- top-2 + renormalize (softmax Z cancels; clip can't bind) ----
    if (tid < TPB) {
        float m1 = -1e30f, m2 = -1e30f;
        int   i1 = 0, i2 = 0;
        for (int e = 0; e < NE; ++e) {
            float v = lg[tid][e];
            if (v > m1)      { m2 = m1; i2 = i1; m1 = v; i1 = e; }
            else if (v > m2) { m2 = v;  i2 = e; }
        }
        float e2  = expf(m2 - m1);
        float inv = 1.f / (1.f + e2);
        int t = t0 + tid;
        out_nv[t * 2 + 0]  = inv;
        out_nv[t * 2 + 1]  = e2 * inv;
        out_idx[t * 2 + 0] = (float)i1;
        out_idx[t * 2 + 1] = (float)i2;
    }
}

extern "C" void kernel_launch(void* const* d_in, const int* in_sizes, int n_in,
                              void* d_out, int out_size, void* d_ws, size_t ws_size,
                              hipStream_t stream) {
    const float* X = (const float*)d_in[0];
    const float* W = (const float*)d_in[1];
    const float* B = (const float*)d_in[2];
    float* out = (float*)d_out;

    unsigned short* WH = (unsigned short*)d_ws;          // 131072 x 2B = 256 KB
    unsigned short* WL = WH + (size_t)DIM * NE;          // +256 KB

    hipLaunchKernelGGL(pack_w, dim3((DIM * NE + 255) / 256), dim3(256), 0, stream, W, WH, WL);
    hipLaunchKernelGGL(router_mfma, dim3(NTOK / TPB), dim3(1024), 0, stream, X, WH, WL, B, out);
}

// Round 5
// 50.566 us; speedup vs baseline: 5.7680x; 1.1288x over previous
//
#include <hip/hip_runtime.h>
#include <hip/hip_bf16.h>

#define NTOK 16384
#define DIM  2048
#define NE   64
#define TPB  16                // tokens per block (one 16-row MFMA tile)
#define KG   8                 // K-split across the 8 waves of a block
#define KPW  (DIM / KG)        // 256 k per wave
#define KSTEPS (KPW / 32)      // 8 mfma k-steps per wave
#define NKS_ALL (DIM / 32)     // 64 total k-steps
#define LP   65

typedef __attribute__((ext_vector_type(8))) short  short8;   // 8 bf16 (4 VGPRs)
typedef __attribute__((ext_vector_type(4))) float  f32x4;

static __device__ __forceinline__ unsigned short f2bf(float f) {
    unsigned u = __float_as_uint(f);
    unsigned r = (u + 0x7fffu + ((u >> 16) & 1u)) >> 16;   // RNE
    return (unsigned short)r;
}
static __device__ __forceinline__ float bf2f(unsigned short h) {
    return __uint_as_float(((unsigned)h) << 16);
}

// packed split: (x0,x1) -> hi word [bf(x1)|bf(x0)], lo word [bf(r1)|bf(r0)]
static __device__ __forceinline__ void cvt_pair(float x0, float x1,
                                                unsigned& hi, unsigned& lo) {
    union { __hip_bfloat162 b; unsigned u; } h, l;
    h.b = __float22bfloat162_rn(float2{x0, x1});           // v_cvt_pk_bf16_f32
    float h0 = __uint_as_float(h.u << 16);                 // elem0 as fp32
    float h1 = __uint_as_float(h.u & 0xffff0000u);         // elem1 as fp32
    l.b = __float22bfloat162_rn(float2{x0 - h0, x1 - h1});
    hi = h.u; lo = l.u;
}

// ---- prologue: split W into hi/lo bf16, packed in MFMA B-fragment order ----
// B-frag (16x16x32): lane l holds col=l&15, k=(l>>4)*8+j
__global__ void pack_w(const float* __restrict__ W,
                       unsigned short* __restrict__ WH,
                       unsigned short* __restrict__ WL) {
    int idx = blockIdx.x * 256 + threadIdx.x;
    if (idx >= DIM * NE) return;
    int k = idx / NE, e = idx % NE;
    float w = W[idx];
    unsigned short h = f2bf(w);
    unsigned short l = f2bf(w - bf2f(h));
    int etile = e >> 4, col = e & 15;
    int kstep = k >> 5, lsub = (k >> 3) & 3, j = k & 7;
    size_t off = (((size_t)etile * NKS_ALL + kstep) * 64 + (lsub * 16 + col)) * 8 + j;
    WH[off] = h;
    WL[off] = l;
}

// ---- main: 3-pass split-bf16 MFMA router, 8 waves/SIMD ----
__global__ __launch_bounds__(512, 8) void router_mfma(
    const float* __restrict__ X,
    const unsigned short* __restrict__ WH,
    const unsigned short* __restrict__ WL,
    const float* __restrict__ B, float* __restrict__ out)
{
    __shared__ float red[KG][TPB][LP];   // 33.3 KB k-partials
    __shared__ float lg[TPB][LP];        // 4.2 KB logits

    const int tid  = threadIdx.x;
    const int lane = tid & 63;
    const int kg   = __builtin_amdgcn_readfirstlane(tid >> 6);  // wave = k group 0..7
    const int t0   = blockIdx.x * TPB;

    const int arow = lane & 15;          // A row (token in tile)
    const int koff = (lane >> 4) * 8;    // k offset within 32-step

    const float* xp = X + (size_t)(t0 + arow) * DIM + kg * KPW + koff;

    f32x4 acc[4];
#pragma unroll
    for (int et = 0; et < 4; ++et) acc[et] = (f32x4){0.f, 0.f, 0.f, 0.f};

#pragma unroll 2
    for (int s = 0; s < KSTEPS; ++s) {
        float4 xa = *(const float4*)(xp + s * 32);
        float4 xb = *(const float4*)(xp + s * 32 + 4);
        unsigned h[4], l[4];
        cvt_pair(xa.x, xa.y, h[0], l[0]);
        cvt_pair(xa.z, xa.w, h[1], l[1]);
        cvt_pair(xb.x, xb.y, h[2], l[2]);
        cvt_pair(xb.z, xb.w, h[3], l[3]);
        union { unsigned u[4]; short8 s8; } ah, al;
#pragma unroll
        for (int j = 0; j < 4; ++j) { ah.u[j] = h[j]; al.u[j] = l[j]; }

        const int ks = kg * KSTEPS + s;
#pragma unroll
        for (int et = 0; et < 4; ++et) {
            size_t foff = (((size_t)et * NKS_ALL + ks) * 64 + lane) * 8;
            short8 bh = *(const short8*)(WH + foff);   // coalesced dwordx4
            short8 bl = *(const short8*)(WL + foff);
            acc[et] = __builtin_amdgcn_mfma_f32_16x16x32_bf16(ah.s8, bh, acc[et], 0, 0, 0);
            acc[et] = __builtin_amdgcn_mfma_f32_16x16x32_bf16(ah.s8, bl, acc[et], 0, 0, 0);
            acc[et] = __builtin_amdgcn_mfma_f32_16x16x32_bf16(al.s8, bh, acc[et], 0, 0, 0);
        }
    }

    // C frag: col = lane&15, row = (lane>>4)*4 + r  (verified R4)
#pragma unroll
    for (int et = 0; et < 4; ++et)
#pragma unroll
        for (int r = 0; r < 4; ++r)
            red[kg][(lane >> 4) * 4 + r][et * 16 + (lane & 15)] = acc[et][r];
    __syncthreads();

    float* out_nv  = out + (size_t)NTOK * NE;
    float* out_idx = out_nv + (size_t)NTOK * 2;

    // ---- reduce over KG, add bias, store logits (coalesced float4) ----
    if (tid < 256) {
        const int rt = tid >> 4;          // token 0..15
        const int re = (tid & 15) * 4;    // expert col
        float4 s = {0.f, 0.f, 0.f, 0.f};
#pragma unroll
        for (int g = 0; g < KG; ++g) {
            s.x += red[g][rt][re + 0];
            s.y += red[g][rt][re + 1];
            s.z += red[g][rt][re + 2];
            s.w += red[g][rt][re + 3];
        }
        float4 bb = *(const float4*)(B + re);
        s.x += bb.x; s.y += bb.y; s.z += bb.z; s.w += bb.w;
        *(float4*)&out[(size_t)(t0 + rt) * NE + re] = s;
        lg[rt][re + 0] = s.x;
        lg[rt][re + 1] = s.y;
        lg[rt][re + 2] = s.z;
        lg[rt][re + 3] = s.w;
    }
    __syncthreads();

    // ---- top-2 + renormalize (softmax Z cancels; clip can't bind) ----
    if (tid < TPB) {
        float m1 = -1e30f, m2 = -1e30f;
        int   i1 = 0, i2 = 0;
        for (int e = 0; e < NE; ++e) {
            float v = lg[tid][e];
            if (v > m1)      { m2 = m1; i2 = i1; m1 = v; i1 = e; }
            else if (v > m2) { m2 = v;  i2 = e; }
        }
        float e2  = expf(m2 - m1);
        float inv = 1.f / (1.f + e2);
        int t = t0 + tid;
        out_nv[t * 2 + 0]  = inv;
        out_nv[t * 2 + 1]  = e2 * inv;
        out_idx[t * 2 + 0] = (float)i1;
        out_idx[t * 2 + 1] = (float)i2;
    }
}

extern "C" void kernel_launch(void* const* d_in, const int* in_sizes, int n_in,
                              void* d_out, int out_size, void* d_ws, size_t ws_size,
                              hipStream_t stream) {
    const float* X = (const float*)d_in[0];
    const float* W = (const float*)d_in[1];
    const float* B = (const float*)d_in[2];
    float* out = (float*)d_out;

    unsigned short* WH = (unsigned short*)d_ws;          // 256 KB
    unsigned short* WL = WH + (size_t)DIM * NE;          // +256 KB

    hipLaunchKernelGGL(pack_w, dim3((DIM * NE + 255) / 256), dim3(256), 0, stream, W, WH, WL);
    hipLaunchKernelGGL(router_mfma, dim3(NTOK / TPB), dim3(512), 0, stream, X, WH, WL, B, out);
}

// Round 6
// 41.919 us; speedup vs baseline: 6.9578x; 1.2063x over previous
//
#include <hip/hip_runtime.h>
#include <hip/hip_bf16.h>

#define NTOK 16384
#define DIM  2048
#define NE   64
#define TPB  32                // tokens per block = 2 MFMA row-tiles
#define NTILE 2
#define KG   8                 // K-split across the 8 waves
#define KPW  (DIM / KG)        // 256 k per wave
#define KSTEPS (KPW / 32)      // 8 mfma k-steps per wave
#define NKS_ALL (DIM / 32)     // 64 total k-steps
#define LP   65

typedef __attribute__((ext_vector_type(8))) short  short8;   // 8 bf16 (4 VGPRs)
typedef __attribute__((ext_vector_type(4))) float  f32x4;

static __device__ __forceinline__ unsigned short f2bf(float f) {
    unsigned u = __float_as_uint(f);
    unsigned r = (u + 0x7fffu + ((u >> 16) & 1u)) >> 16;   // RNE
    return (unsigned short)r;
}
static __device__ __forceinline__ float bf2f(unsigned short h) {
    return __uint_as_float(((unsigned)h) << 16);
}

// packed split: (x0,x1) -> hi word [bf(x1)|bf(x0)], lo word [bf(r1)|bf(r0)]
static __device__ __forceinline__ void cvt_pair(float x0, float x1,
                                                unsigned& hi, unsigned& lo) {
    union { __hip_bfloat162 b; unsigned u; } h, l;
    h.b = __float22bfloat162_rn(float2{x0, x1});           // v_cvt_pk_bf16_f32
    float h0 = __uint_as_float(h.u << 16);
    float h1 = __uint_as_float(h.u & 0xffff0000u);
    l.b = __float22bfloat162_rn(float2{x0 - h0, x1 - h1});
    hi = h.u; lo = l.u;
}

// ---- prologue: split W into hi/lo bf16, packed in MFMA B-fragment order ----
__global__ void pack_w(const float* __restrict__ W,
                       unsigned short* __restrict__ WH,
                       unsigned short* __restrict__ WL) {
    int idx = blockIdx.x * 256 + threadIdx.x;
    if (idx >= DIM * NE) return;
    int k = idx / NE, e = idx % NE;
    float w = W[idx];
    unsigned short h = f2bf(w);
    unsigned short l = f2bf(w - bf2f(h));
    int etile = e >> 4, col = e & 15;
    int kstep = k >> 5, lsub = (k >> 3) & 3, j = k & 7;
    size_t off = (((size_t)etile * NKS_ALL + kstep) * 64 + (lsub * 16 + col)) * 8 + j;
    WH[off] = h;
    WL[off] = l;
}

// ---- main: 3-pass split-bf16 MFMA router, 2 tiles/wave for B reuse + ILP ----
__global__ __launch_bounds__(512, 4) void router_mfma(
    const float* __restrict__ X,
    const unsigned short* __restrict__ WH,
    const unsigned short* __restrict__ WL,
    const float* __restrict__ B, float* __restrict__ out)
{
    __shared__ float red[KG][TPB][LP];   // 66.6 KB k-partials
    __shared__ float lg[TPB][LP];        // 8.3 KB logits

    const int tid  = threadIdx.x;
    const int lane = tid & 63;
    const int kg   = __builtin_amdgcn_readfirstlane(tid >> 6);  // wave = k group 0..7
    const int t0   = blockIdx.x * TPB;

    const int arow = lane & 15;          // A row within tile
    const int koff = (lane >> 4) * 8;    // k offset within 32-step

    const float* xp0 = X + (size_t)(t0 + arow) * DIM + kg * KPW + koff;
    const float* xp1 = xp0 + (size_t)16 * DIM;

    f32x4 acc[NTILE][4];
#pragma unroll
    for (int t = 0; t < NTILE; ++t)
#pragma unroll
        for (int et = 0; et < 4; ++et) acc[t][et] = (f32x4){0.f, 0.f, 0.f, 0.f};

#pragma unroll 2
    for (int s = 0; s < KSTEPS; ++s) {
        // ---- issue all loads for this k-step up front (12 independent) ----
        float4 xa0 = *(const float4*)(xp0 + s * 32);
        float4 xb0 = *(const float4*)(xp0 + s * 32 + 4);
        float4 xa1 = *(const float4*)(xp1 + s * 32);
        float4 xb1 = *(const float4*)(xp1 + s * 32 + 4);

        const int ks = kg * KSTEPS + s;
        short8 bh[4], bl[4];
#pragma unroll
        for (int et = 0; et < 4; ++et) {
            size_t foff = (((size_t)et * NKS_ALL + ks) * 64 + lane) * 8;
            bh[et] = *(const short8*)(WH + foff);
            bl[et] = *(const short8*)(WL + foff);
        }

        // ---- convert A (VALU work overlaps B-load latency) ----
        union { unsigned u[4]; short8 s8; } ah[NTILE], al[NTILE];
        cvt_pair(xa0.x, xa0.y, ah[0].u[0], al[0].u[0]);
        cvt_pair(xa0.z, xa0.w, ah[0].u[1], al[0].u[1]);
        cvt_pair(xb0.x, xb0.y, ah[0].u[2], al[0].u[2]);
        cvt_pair(xb0.z, xb0.w, ah[0].u[3], al[0].u[3]);
        cvt_pair(xa1.x, xa1.y, ah[1].u[0], al[1].u[0]);
        cvt_pair(xa1.z, xa1.w, ah[1].u[1], al[1].u[1]);
        cvt_pair(xb1.x, xb1.y, ah[1].u[2], al[1].u[2]);
        cvt_pair(xb1.z, xb1.w, ah[1].u[3], al[1].u[3]);

        // ---- 24-MFMA burst: B reused across 2 tiles ----
#pragma unroll
        for (int et = 0; et < 4; ++et) {
#pragma unroll
            for (int t = 0; t < NTILE; ++t) {
                acc[t][et] = __builtin_amdgcn_mfma_f32_16x16x32_bf16(ah[t].s8, bh[et], acc[t][et], 0, 0, 0);
                acc[t][et] = __builtin_amdgcn_mfma_f32_16x16x32_bf16(ah[t].s8, bl[et], acc[t][et], 0, 0, 0);
                acc[t][et] = __builtin_amdgcn_mfma_f32_16x16x32_bf16(al[t].s8, bh[et], acc[t][et], 0, 0, 0);
            }
        }
    }

    // C frag: col = lane&15, row = (lane>>4)*4 + r
#pragma unroll
    for (int t = 0; t < NTILE; ++t)
#pragma unroll
        for (int et = 0; et < 4; ++et)
#pragma unroll
            for (int r = 0; r < 4; ++r)
                red[kg][t * 16 + (lane >> 4) * 4 + r][et * 16 + (lane & 15)] = acc[t][et][r];
    __syncthreads();

    float* out_nv  = out + (size_t)NTOK * NE;
    float* out_idx = out_nv + (size_t)NTOK * 2;

    // ---- reduce over KG, add bias, store logits (512 threads = 32 tok x 16 cols) ----
    {
        const int rt = tid >> 4;
        const int re = (tid & 15) * 4;
        float4 s = {0.f, 0.f, 0.f, 0.f};
#pragma unroll
        for (int g = 0; g < KG; ++g) {
            s.x += red[g][rt][re + 0];
            s.y += red[g][rt][re + 1];
            s.z += red[g][rt][re + 2];
            s.w += red[g][rt][re + 3];
        }
        float4 bb = *(const float4*)(B + re);
        s.x += bb.x; s.y += bb.y; s.z += bb.z; s.w += bb.w;
        *(float4*)&out[(size_t)(t0 + rt) * NE + re] = s;
        lg[rt][re + 0] = s.x;
        lg[rt][re + 1] = s.y;
        lg[rt][re + 2] = s.z;
        lg[rt][re + 3] = s.w;
    }
    __syncthreads();

    // ---- top-2 + renormalize (softmax Z cancels; clip can't bind) ----
    if (tid < TPB) {
        float m1 = -1e30f, m2 = -1e30f;
        int   i1 = 0, i2 = 0;
        for (int e = 0; e < NE; ++e) {
            float v = lg[tid][e];
            if (v > m1)      { m2 = m1; i2 = i1; m1 = v; i1 = e; }
            else if (v > m2) { m2 = v;  i2 = e; }
        }
        float e2  = expf(m2 - m1);
        float inv = 1.f / (1.f + e2);
        int t = t0 + tid;
        out_nv[t * 2 + 0]  = inv;
        out_nv[t * 2 + 1]  = e2 * inv;
        out_idx[t * 2 + 0] = (float)i1;
        out_idx[t * 2 + 1] = (float)i2;
    }
}

extern "C" void kernel_launch(void* const* d_in, const int* in_sizes, int n_in,
                              void* d_out, int out_size, void* d_ws, size_t ws_size,
                              hipStream_t stream) {
    const float* X = (const float*)d_in[0];
    const float* W = (const float*)d_in[1];
    const float* B = (const float*)d_in[2];
    float* out = (float*)d_out;

    unsigned short* WH = (unsigned short*)d_ws;          // 256 KB
    unsigned short* WL = WH + (size_t)DIM * NE;          // +256 KB

    hipLaunchKernelGGL(pack_w, dim3((DIM * NE + 255) / 256), dim3(256), 0, stream, W, WH, WL);
    hipLaunchKernelGGL(router_mfma, dim3(NTOK / TPB), dim3(512), 0, stream, X, WH, WL, B, out);
}

// Round 7
// 38.795 us; speedup vs baseline: 7.5182x; 1.0805x over previous
//
#include <hip/hip_runtime.h>
#include <hip/hip_bf16.h>

#define NTOK 16384
#define DIM  2048
#define NE   64
#define TPB  64                // tokens per block (2 halves x 2 tiles)
#define NTILE 2
#define KG   8                 // K-split across kg waves
#define KPW  (DIM / KG)        // 256 k per wave
#define KSTEPS (KPW / 32)      // 8 mfma k-steps per wave
#define NKS_ALL (DIM / 32)     // 64 total k-steps
#define LP   65

typedef __attribute__((ext_vector_type(8))) short  short8;   // 8 bf16 (4 VGPRs)
typedef __attribute__((ext_vector_type(4))) float  f32x4;

static __device__ __forceinline__ unsigned short f2bf(float f) {
    unsigned u = __float_as_uint(f);
    unsigned r = (u + 0x7fffu + ((u >> 16) & 1u)) >> 16;   // RNE
    return (unsigned short)r;
}
static __device__ __forceinline__ float bf2f(unsigned short h) {
    return __uint_as_float(((unsigned)h) << 16);
}

// packed split: (x0,x1) -> hi word [bf(x1)|bf(x0)], lo word [bf(r1)|bf(r0)]
static __device__ __forceinline__ void cvt_pair(float x0, float x1,
                                                unsigned& hi, unsigned& lo) {
    union { __hip_bfloat162 b; unsigned u; } h, l;
    h.b = __float22bfloat162_rn(float2{x0, x1});           // v_cvt_pk_bf16_f32
    float h0 = __uint_as_float(h.u << 16);
    float h1 = __uint_as_float(h.u & 0xffff0000u);
    l.b = __float22bfloat162_rn(float2{x0 - h0, x1 - h1});
    hi = h.u; lo = l.u;
}

// ---- prologue: split W into hi/lo bf16, packed in MFMA B-fragment order ----
__global__ void pack_w(const float* __restrict__ W,
                       unsigned short* __restrict__ WH,
                       unsigned short* __restrict__ WL) {
    int idx = blockIdx.x * 256 + threadIdx.x;
    if (idx >= DIM * NE) return;
    int k = idx / NE, e = idx % NE;
    float w = W[idx];
    unsigned short h = f2bf(w);
    unsigned short l = f2bf(w - bf2f(h));
    int etile = e >> 4, col = e & 15;
    int kstep = k >> 5, lsub = (k >> 3) & 3, j = k & 7;
    size_t off = (((size_t)etile * NKS_ALL + kstep) * 64 + (lsub * 16 + col)) * 8 + j;
    WH[off] = h;
    WL[off] = l;
}

// ---- main: 3-pass split-bf16 MFMA router; 16 waves = 8 kg x 2 token-halves ----
__global__ __launch_bounds__(1024, 4) void router_mfma(
    const float* __restrict__ X,
    const unsigned short* __restrict__ WH,
    const unsigned short* __restrict__ WL,
    const float* __restrict__ B, float* __restrict__ out)
{
    __shared__ float red[KG][TPB][LP];   // 133.1 KB k-partials
    __shared__ float lg[TPB][LP];        // 16.6 KB logits

    const int tid  = threadIdx.x;
    const int lane = tid & 63;
    const int wv   = tid >> 6;                                  // 0..15
    const int kg   = __builtin_amdgcn_readfirstlane(wv & 7);    // k group 0..7
    const int th   = __builtin_amdgcn_readfirstlane(wv >> 3);   // token half 0..1
    const int t0   = blockIdx.x * TPB;

    const int arow = lane & 15;          // A row within 16-tile
    const int koff = (lane >> 4) * 8;    // k offset within 32-step

    const float* xp0 = X + (size_t)(t0 + th * 32 + arow) * DIM + kg * KPW + koff;
    const float* xp1 = xp0 + (size_t)16 * DIM;

    f32x4 acc[NTILE][4];
#pragma unroll
    for (int t = 0; t < NTILE; ++t)
#pragma unroll
        for (int et = 0; et < 4; ++et) acc[t][et] = (f32x4){0.f, 0.f, 0.f, 0.f};

#pragma unroll 2
    for (int s = 0; s < KSTEPS; ++s) {
        // ---- issue all loads for this k-step up front ----
        float4 xa0 = *(const float4*)(xp0 + s * 32);
        float4 xb0 = *(const float4*)(xp0 + s * 32 + 4);
        float4 xa1 = *(const float4*)(xp1 + s * 32);
        float4 xb1 = *(const float4*)(xp1 + s * 32 + 4);

        const int ks = kg * KSTEPS + s;
        short8 bh[4], bl[4];
#pragma unroll
        for (int et = 0; et < 4; ++et) {
            size_t foff = (((size_t)et * NKS_ALL + ks) * 64 + lane) * 8;
            bh[et] = *(const short8*)(WH + foff);
            bl[et] = *(const short8*)(WL + foff);
        }

        // ---- convert A (VALU overlaps B-load latency) ----
        union { unsigned u[4]; short8 s8; } ah[NTILE], al[NTILE];
        cvt_pair(xa0.x, xa0.y, ah[0].u[0], al[0].u[0]);
        cvt_pair(xa0.z, xa0.w, ah[0].u[1], al[0].u[1]);
        cvt_pair(xb0.x, xb0.y, ah[0].u[2], al[0].u[2]);
        cvt_pair(xb0.z, xb0.w, ah[0].u[3], al[0].u[3]);
        cvt_pair(xa1.x, xa1.y, ah[1].u[0], al[1].u[0]);
        cvt_pair(xa1.z, xa1.w, ah[1].u[1], al[1].u[1]);
        cvt_pair(xb1.x, xb1.y, ah[1].u[2], al[1].u[2]);
        cvt_pair(xb1.z, xb1.w, ah[1].u[3], al[1].u[3]);

        // ---- 24-MFMA burst: B reused across 2 tiles (and across th waves via L1) ----
#pragma unroll
        for (int et = 0; et < 4; ++et) {
#pragma unroll
            for (int t = 0; t < NTILE; ++t) {
                acc[t][et] = __builtin_amdgcn_mfma_f32_16x16x32_bf16(ah[t].s8, bh[et], acc[t][et], 0, 0, 0);
                acc[t][et] = __builtin_amdgcn_mfma_f32_16x16x32_bf16(ah[t].s8, bl[et], acc[t][et], 0, 0, 0);
                acc[t][et] = __builtin_amdgcn_mfma_f32_16x16x32_bf16(al[t].s8, bh[et], acc[t][et], 0, 0, 0);
            }
        }
    }

    // C frag: col = lane&15, row = (lane>>4)*4 + r
#pragma unroll
    for (int t = 0; t < NTILE; ++t)
#pragma unroll
        for (int et = 0; et < 4; ++et)
#pragma unroll
            for (int r = 0; r < 4; ++r)
                red[kg][th * 32 + t * 16 + (lane >> 4) * 4 + r][et * 16 + (lane & 15)] = acc[t][et][r];
    __syncthreads();

    float* out_nv  = out + (size_t)NTOK * NE;
    float* out_idx = out_nv + (size_t)NTOK * 2;

    // ---- reduce over KG, add bias, store logits (1024 thr = 64 tok x 16 cols) ----
    {
        const int rt = tid >> 4;
        const int re = (tid & 15) * 4;
        float4 s = {0.f, 0.f, 0.f, 0.f};
#pragma unroll
        for (int g = 0; g < KG; ++g) {
            s.x += red[g][rt][re + 0];
            s.y += red[g][rt][re + 1];
            s.z += red[g][rt][re + 2];
            s.w += red[g][rt][re + 3];
        }
        float4 bb = *(const float4*)(B + re);
        s.x += bb.x; s.y += bb.y; s.z += bb.z; s.w += bb.w;
        *(float4*)&out[(size_t)(t0 + rt) * NE + re] = s;
        lg[rt][re + 0] = s.x;
        lg[rt][re + 1] = s.y;
        lg[rt][re + 2] = s.z;
        lg[rt][re + 3] = s.w;
    }
    __syncthreads();

    // ---- top-2 + renormalize: 4 lanes/token, shfl-merge (lowest-index ties) ----
    if (tid < 4 * TPB) {
        const int tt = tid >> 2;         // token 0..63
        const int q  = tid & 3;          // expert quarter
        float m1 = -1e30f, m2 = -1e30f;
        int   i1 = 0, i2 = 0;
#pragma unroll
        for (int j = 0; j < 16; ++j) {
            int   e = q * 16 + j;
            float v = lg[tt][e];
            if (v > m1)      { m2 = m1; i2 = i1; m1 = v; i1 = e; }
            else if (v > m2) { m2 = v;  i2 = e; }
        }
#pragma unroll
        for (int d = 1; d <= 2; d <<= 1) {
            float om1 = __shfl_xor(m1, d);
            int   oi1 = __shfl_xor(i1, d);
            float om2 = __shfl_xor(m2, d);
            int   oi2 = __shfl_xor(i2, d);
            bool agt = (m1 > om1) || (m1 == om1 && i1 < oi1);
            float a1 = agt ? m1 : om1;  int ai1 = agt ? i1 : oi1;
            float c2 = agt ? m2 : om2;  int ci2 = agt ? i2 : oi2;   // loser pool: runner-up of winner
            float c1 = agt ? om1 : m1;  int ci1 = agt ? oi1 : i1;   // loser's best
            bool sgt = (c2 > c1) || (c2 == c1 && ci2 < ci1);
            m1 = a1; i1 = ai1;
            m2 = sgt ? c2 : c1; i2 = sgt ? ci2 : ci1;
        }
        if (q == 0) {
            float e2  = expf(m2 - m1);
            float inv = 1.f / (1.f + e2);
            int t = t0 + tt;
            out_nv[t * 2 + 0]  = inv;
            out_nv[t * 2 + 1]  = e2 * inv;
            out_idx[t * 2 + 0] = (float)i1;
            out_idx[t * 2 + 1] = (float)i2;
        }
    }
}

extern "C" void kernel_launch(void* const* d_in, const int* in_sizes, int n_in,
                              void* d_out, int out_size, void* d_ws, size_t ws_size,
                              hipStream_t stream) {
    const float* X = (const float*)d_in[0];
    const float* W = (const float*)d_in[1];
    const float* B = (const float*)d_in[2];
    float* out = (float*)d_out;

    unsigned short* WH = (unsigned short*)d_ws;          // 256 KB
    unsigned short* WL = WH + (size_t)DIM * NE;          // +256 KB

    hipLaunchKernelGGL(pack_w, dim3((DIM * NE + 255) / 256), dim3(256), 0, stream, W, WH, WL);
    hipLaunchKernelGGL(router_mfma, dim3(NTOK / TPB), dim3(1024), 0, stream, X, WH, WL, B, out);
}

// Round 8
// 36.711 us; speedup vs baseline: 7.9450x; 1.0568x over previous
//
#include <hip/hip_runtime.h>
#include <hip/hip_bf16.h>

#define NTOK 16384
#define DIM  2048
#define NE   64
#define TPB  64                // tokens per block = 4 tiles, one block per CU
#define NTILE 4
#define KG   8                 // wave = k-group
#define KPW  (DIM / KG)        // 256 k per wave
#define KSTEPS (KPW / 32)      // 8 mfma k-steps per wave
#define NKS_ALL (DIM / 32)     // 64 total k-steps
#define LP   65

typedef __attribute__((ext_vector_type(8))) short  short8;   // 8 bf16 (4 VGPRs)
typedef __attribute__((ext_vector_type(4))) float  f32x4;

static __device__ __forceinline__ unsigned short f2bf(float f) {
    unsigned u = __float_as_uint(f);
    unsigned r = (u + 0x7fffu + ((u >> 16) & 1u)) >> 16;   // RNE
    return (unsigned short)r;
}
static __device__ __forceinline__ float bf2f(unsigned short h) {
    return __uint_as_float(((unsigned)h) << 16);
}

// packed split: (x0,x1) -> hi word [bf(x1)|bf(x0)], lo word [bf(r1)|bf(r0)]
static __device__ __forceinline__ void cvt_pair(float x0, float x1,
                                                unsigned& hi, unsigned& lo) {
    union { __hip_bfloat162 b; unsigned u; } h, l;
    h.b = __float22bfloat162_rn(float2{x0, x1});           // v_cvt_pk_bf16_f32
    float h0 = __uint_as_float(h.u << 16);
    float h1 = __uint_as_float(h.u & 0xffff0000u);
    l.b = __float22bfloat162_rn(float2{x0 - h0, x1 - h1});
    hi = h.u; lo = l.u;
}

// ---- prologue: split W into hi/lo bf16, packed in MFMA B-fragment order ----
__global__ void pack_w(const float* __restrict__ W,
                       unsigned short* __restrict__ WH,
                       unsigned short* __restrict__ WL) {
    int idx = blockIdx.x * 256 + threadIdx.x;
    if (idx >= DIM * NE) return;
    int k = idx / NE, e = idx % NE;
    float w = W[idx];
    unsigned short h = f2bf(w);
    unsigned short l = f2bf(w - bf2f(h));
    int etile = e >> 4, col = e & 15;
    int kstep = k >> 5, lsub = (k >> 3) & 3, j = k & 7;
    size_t off = (((size_t)etile * NKS_ALL + kstep) * 64 + (lsub * 16 + col)) * 8 + j;
    WH[off] = h;
    WL[off] = l;
}

// ---- main: 3-pass split-bf16 MFMA; 8 waves, NTILE=4, depth-2 reg pipeline ----
__global__ __launch_bounds__(512, 2) void router_mfma(
    const float* __restrict__ X,
    const unsigned short* __restrict__ WH,
    const unsigned short* __restrict__ WL,
    const float* __restrict__ B, float* __restrict__ out)
{
    __shared__ float red[KG][TPB][LP];   // 130 KiB k-partials (lg folded into red[0])

    const int tid  = threadIdx.x;
    const int lane = tid & 63;
    const int kg   = __builtin_amdgcn_readfirstlane(tid >> 6);  // wave = k group 0..7
    const int t0   = blockIdx.x * TPB;

    const int arow = lane & 15;          // A row within 16-tile
    const int koff = (lane >> 4) * 8;    // k offset within 32-step

    const float* xp0 = X + (size_t)(t0 +  0 + arow) * DIM + kg * KPW + koff;
    const float* xp1 = X + (size_t)(t0 + 16 + arow) * DIM + kg * KPW + koff;
    const float* xp2 = X + (size_t)(t0 + 32 + arow) * DIM + kg * KPW + koff;
    const float* xp3 = X + (size_t)(t0 + 48 + arow) * DIM + kg * KPW + koff;

    const int ksbase = kg * KSTEPS;

    f32x4 acc[NTILE][4];
#pragma unroll
    for (int t = 0; t < NTILE; ++t)
#pragma unroll
        for (int et = 0; et < 4; ++et) acc[t][et] = (f32x4){0.f, 0.f, 0.f, 0.f};

    float4 xA[NTILE][2], xB[NTILE][2];
    short8 bhA[4], blA[4], bhB[4], blB[4];

#define LOADX(buf, s) do {                                                    \
    buf[0][0] = *(const float4*)(xp0 + (s) * 32);                             \
    buf[0][1] = *(const float4*)(xp0 + (s) * 32 + 4);                         \
    buf[1][0] = *(const float4*)(xp1 + (s) * 32);                             \
    buf[1][1] = *(const float4*)(xp1 + (s) * 32 + 4);                         \
    buf[2][0] = *(const float4*)(xp2 + (s) * 32);                             \
    buf[2][1] = *(const float4*)(xp2 + (s) * 32 + 4);                         \
    buf[3][0] = *(const float4*)(xp3 + (s) * 32);                             \
    buf[3][1] = *(const float4*)(xp3 + (s) * 32 + 4);                         \
  } while (0)

#define LOADB(bh_, bl_, s) do {                                               \
    _Pragma("unroll")                                                         \
    for (int et = 0; et < 4; ++et) {                                          \
        size_t foff = (((size_t)et * NKS_ALL + ksbase + (s)) * 64 + lane) * 8;\
        bh_[et] = *(const short8*)(WH + foff);                                \
        bl_[et] = *(const short8*)(WL + foff);                                \
    }                                                                         \
  } while (0)

#define COMPUTE(xv, bh_, bl_) do {                                            \
    union { unsigned u[4]; short8 s8; } ah[NTILE], al[NTILE];                 \
    _Pragma("unroll")                                                         \
    for (int t = 0; t < NTILE; ++t) {                                         \
        cvt_pair(xv[t][0].x, xv[t][0].y, ah[t].u[0], al[t].u[0]);             \
        cvt_pair(xv[t][0].z, xv[t][0].w, ah[t].u[1], al[t].u[1]);             \
        cvt_pair(xv[t][1].x, xv[t][1].y, ah[t].u[2], al[t].u[2]);             \
        cvt_pair(xv[t][1].z, xv[t][1].w, ah[t].u[3], al[t].u[3]);             \
    }                                                                         \
    _Pragma("unroll")                                                         \
    for (int et = 0; et < 4; ++et) {                                          \
        _Pragma("unroll")                                                     \
        for (int t = 0; t < NTILE; ++t) {                                     \
            acc[t][et] = __builtin_amdgcn_mfma_f32_16x16x32_bf16(ah[t].s8, bh_[et], acc[t][et], 0, 0, 0); \
            acc[t][et] = __builtin_amdgcn_mfma_f32_16x16x32_bf16(ah[t].s8, bl_[et], acc[t][et], 0, 0, 0); \
            acc[t][et] = __builtin_amdgcn_mfma_f32_16x16x32_bf16(al[t].s8, bh_[et], acc[t][et], 0, 0, 0); \
        }                                                                     \
    }                                                                         \
  } while (0)

    // depth-2 pipeline: loads for step s+1 issue before compute of step s
    LOADX(xA, 0); LOADB(bhA, blA, 0);
#pragma unroll
    for (int ii = 0; ii < KSTEPS / 2; ++ii) {
        LOADX(xB, 2 * ii + 1); LOADB(bhB, blB, 2 * ii + 1);
        COMPUTE(xA, bhA, blA);
        if (ii < KSTEPS / 2 - 1) { LOADX(xA, 2 * ii + 2); LOADB(bhA, blA, 2 * ii + 2); }
        COMPUTE(xB, bhB, blB);
    }

    // C frag: col = lane&15, row = (lane>>4)*4 + r
#pragma unroll
    for (int t = 0; t < NTILE; ++t)
#pragma unroll
        for (int et = 0; et < 4; ++et)
#pragma unroll
            for (int r = 0; r < 4; ++r)
                red[kg][t * 16 + (lane >> 4) * 4 + r][et * 16 + (lane & 15)] = acc[t][et][r];
    __syncthreads();

    float* out_nv  = out + (size_t)NTOK * NE;
    float* out_idx = out_nv + (size_t)NTOK * 2;

    // ---- reduce over KG, add bias, store logits; write winners back into red[0] ----
#pragma unroll
    for (int k = 0; k < 2; ++k) {
        const int idx = tid + k * 512;    // 1024 items: 64 tok x 16 col-quads
        const int rt = idx >> 4;
        const int re = (idx & 15) * 4;
        float4 s = {0.f, 0.f, 0.f, 0.f};
#pragma unroll
        for (int g = 0; g < KG; ++g) {
            s.x += red[g][rt][re + 0];
            s.y += red[g][rt][re + 1];
            s.z += red[g][rt][re + 2];
            s.w += red[g][rt][re + 3];
        }
        float4 bb = *(const float4*)(B + re);
        s.x += bb.x; s.y += bb.y; s.z += bb.z; s.w += bb.w;
        *(float4*)&out[(size_t)(t0 + rt) * NE + re] = s;
        red[0][rt][re + 0] = s.x;     // each slot owned by exactly this thread
        red[0][rt][re + 1] = s.y;
        red[0][rt][re + 2] = s.z;
        red[0][rt][re + 3] = s.w;
    }
    __syncthreads();

    // ---- top-2 + renormalize: 4 lanes/token, shfl-merge (lowest-index ties) ----
    if (tid < 4 * TPB) {
        const int tt = tid >> 2;         // token 0..63
        const int q  = tid & 3;          // expert quarter
        float m1 = -1e30f, m2 = -1e30f;
        int   i1 = 0, i2 = 0;
#pragma unroll
        for (int j = 0; j < 16; ++j) {
            int   e = q * 16 + j;
            float v = red[0][tt][e];
            if (v > m1)      { m2 = m1; i2 = i1; m1 = v; i1 = e; }
            else if (v > m2) { m2 = v;  i2 = e; }
        }
#pragma unroll
        for (int d = 1; d <= 2; d <<= 1) {
            float om1 = __shfl_xor(m1, d);
            int   oi1 = __shfl_xor(i1, d);
            float om2 = __shfl_xor(m2, d);
            int   oi2 = __shfl_xor(i2, d);
            bool agt = (m1 > om1) || (m1 == om1 && i1 < oi1);
            float a1 = agt ? m1 : om1;  int ai1 = agt ? i1 : oi1;
            float c2 = agt ? m2 : om2;  int ci2 = agt ? i2 : oi2;
            float c1 = agt ? om1 : m1;  int ci1 = agt ? oi1 : i1;
            bool sgt = (c2 > c1) || (c2 == c1 && ci2 < ci1);
            m1 = a1; i1 = ai1;
            m2 = sgt ? c2 : c1; i2 = sgt ? ci2 : ci1;
        }
        if (q == 0) {
            float e2  = expf(m2 - m1);
            float inv = 1.f / (1.f + e2);
            int t = t0 + tt;
            out_nv[t * 2 + 0]  = inv;
            out_nv[t * 2 + 1]  = e2 * inv;
            out_idx[t * 2 + 0] = (float)i1;
            out_idx[t * 2 + 1] = (float)i2;
        }
    }
}

extern "C" void kernel_launch(void* const* d_in, const int* in_sizes, int n_in,
                              void* d_out, int out_size, void* d_ws, size_t ws_size,
                              hipStream_t stream) {
    const float* X = (const float*)d_in[0];
    const float* W = (const float*)d_in[1];
    const float* B = (const float*)d_in[2];
    float* out = (float*)d_out;

    unsigned short* WH = (unsigned short*)d_ws;          // 256 KB
    unsigned short* WL = WH + (size_t)DIM * NE;          // +256 KB

    hipLaunchKernelGGL(pack_w, dim3((DIM * NE + 255) / 256), dim3(256), 0, stream, W, WH, WL);
    hipLaunchKernelGGL(router_mfma, dim3(NTOK / TPB), dim3(512), 0, stream, X, WH, WL, B, out);
}